// Round 10
// baseline (226.360 us; speedup 1.0000x reference)
//
#include <hip/hip_runtime.h>
#include <cmath>

#define CNUM 512
#define DNUM 128
#define BNUM 4096
#define EPSV 1e-5f
#define GPBLK 72            // (4096 + 512) / 64 split-K partial blocks

// ---- all intermediates in device globals: no d_ws dependence at all ----
__device__ float g_counts[CNUM];
__device__ float g_mean[CNUM * DNUM];
__device__ float g_lp[CNUM];
__device__ float g_G[DNUM * DNUM];
__device__ float g_Gp[GPBLK * DNUM * DNUM];   // split-K partials, 4.7 MB
__device__ float g_P[DNUM * DNUM];
__device__ float g_Pm[CNUM * DNUM];
__device__ float g_r[CNUM];
__device__ float g_q[BNUM];

// ---- class sums + counts + mean + logprior, no global atomics ----
__global__ __launch_bounds__(256) void k_csum(const float* __restrict__ z, const int* __restrict__ y,
                                              float logtot) {
    const int t = threadIdx.x;
    const int bi = blockIdx.x;
    __shared__ float cnt[CNUM];
    cnt[t] = 0.0f; cnt[t + 256] = 0.0f;
    __syncthreads();
    #pragma unroll
    for (int i = 0; i < 16; ++i) atomicAdd(&cnt[y[i * 256 + t]], 1.0f);
    __syncthreads();
    if (bi < 16) {
        __shared__ float acc[CNUM][8];        // 16 KB
        #pragma unroll
        for (int v = 0; v < 16; ++v) {
            int idx = t + v * 256;
            acc[idx >> 3][idx & 7] = 0.0f;
        }
        __syncthreads();
        const int d0 = bi * 8;
        #pragma unroll
        for (int i = 0; i < 16; ++i) {
            int s = i * 256 + t;
            int yy = y[s];
            const float4* zp = (const float4*)(z + (size_t)s * DNUM + d0);
            float4 a = zp[0], b = zp[1];
            float* dst = &acc[yy][0];
            atomicAdd(dst + 0, a.x); atomicAdd(dst + 1, a.y);
            atomicAdd(dst + 2, a.z); atomicAdd(dst + 3, a.w);
            atomicAdd(dst + 4, b.x); atomicAdd(dst + 5, b.y);
            atomicAdd(dst + 6, b.z); atomicAdd(dst + 7, b.w);
        }
        __syncthreads();
        #pragma unroll
        for (int v = 0; v < 2; ++v) {
            int c = t + v * 256;
            float inv = 1.0f / (cnt[c] + EPSV);
            float4 a0 = *(float4*)&acc[c][0];
            float4 a1 = *(float4*)&acc[c][4];
            *(float4*)&g_mean[(size_t)c * DNUM + d0]     = make_float4(a0.x * inv, a0.y * inv, a0.z * inv, a0.w * inv);
            *(float4*)&g_mean[(size_t)c * DNUM + d0 + 4] = make_float4(a1.x * inv, a1.y * inv, a1.z * inv, a1.w * inv);
        }
    } else {
        #pragma unroll
        for (int v = 0; v < 2; ++v) {
            int c = t + v * 256;
            g_counts[c] = cnt[c];
            g_lp[c] = logf(cnt[c] + EPSV) - logtot;
        }
    }
}

// ---- G split-K partial: rows [b*64, b*64+64) of X=[z; mean], weighted ----
__global__ __launch_bounds__(256) void k_gpart(const float* __restrict__ z) {
    __shared__ float xs[64][132];
    __shared__ float ws[64];
    const int t = threadIdx.x;
    const int R0 = blockIdx.x * 64;
    #pragma unroll
    for (int v = 0; v < 8; ++v) {
        int idx = t + v * 256;
        int r = idx >> 5, f4 = idx & 31;
        int row = R0 + r;
        float4 val;
        if (row < BNUM) {
            val = ((const float4*)z)[(size_t)row * 32 + f4];
            if (f4 == 0) ws[r] = 1.0f;
        } else {
            int c = row - BNUM;
            val = ((const float4*)g_mean)[(size_t)c * 32 + f4];
            if (f4 == 0) ws[r] = -(g_counts[c] + 2.0f * EPSV);
        }
        *(float4*)&xs[r][f4 * 4] = val;
    }
    __syncthreads();
    const int tx = t & 15, ty = t >> 4;
    float acc[8][8] = {};
    #pragma unroll
    for (int s = 0; s < 64; ++s) {
        const float4* pa = (const float4*)&xs[s][ty * 8];
        const float4* pb = (const float4*)&xs[s][tx * 8];
        float w = ws[s];
        float4 t0 = pa[0], t1 = pa[1];
        float4 u0 = pb[0], u1 = pb[1];
        float va[8] = {w * t0.x, w * t0.y, w * t0.z, w * t0.w, w * t1.x, w * t1.y, w * t1.z, w * t1.w};
        float vb[8] = {u0.x, u0.y, u0.z, u0.w, u1.x, u1.y, u1.z, u1.w};
        #pragma unroll
        for (int i = 0; i < 8; ++i)
            #pragma unroll
            for (int j = 0; j < 8; ++j)
                acc[i][j] += va[i] * vb[j];
    }
    float* gp = g_Gp + (size_t)blockIdx.x * DNUM * DNUM;
    #pragma unroll
    for (int i = 0; i < 8; ++i) {
        *(float4*)(gp + (size_t)(ty * 8 + i) * DNUM + tx * 8)     = make_float4(acc[i][0], acc[i][1], acc[i][2], acc[i][3]);
        *(float4*)(gp + (size_t)(ty * 8 + i) * DNUM + tx * 8 + 4) = make_float4(acc[i][4], acc[i][5], acc[i][6], acc[i][7]);
    }
}

// ---------------- reduce 72 partials -> g_G ----------------
__global__ __launch_bounds__(256) void k_greduce() {
    int idx = blockIdx.x * 256 + threadIdx.x;   // 16384 threads
    float s = 0.0f;
    #pragma unroll
    for (int p = 0; p < GPBLK; ++p) s += g_Gp[(size_t)p * DNUM * DNUM + idx];
    g_G[idx] = s;
}

// ---- 4x4 in-register GJ inverse (no pivoting), write to LDS ----
__device__ __forceinline__ void inv4_write(float m[4][4], float* dinvp) {
    #pragma unroll
    for (int k = 0; k < 4; ++k) {
        float d = 1.0f / m[k][k];
        #pragma unroll
        for (int i = 0; i < 4; ++i) {
            if (i == k) continue;
            float c = m[i][k] * d;
            #pragma unroll
            for (int j = 0; j < 4; ++j) if (j != k) m[i][j] -= c * m[k][j];
        }
        #pragma unroll
        for (int j = 0; j < 4; ++j) if (j != k) m[k][j] *= d;
        #pragma unroll
        for (int i = 0; i < 4; ++i) if (i != k) m[i][k] *= -d;
        m[k][k] = d;
    }
    #pragma unroll
    for (int i = 0; i < 4; ++i)
        #pragma unroll
        for (int j = 0; j < 4; ++j) dinvp[i * 4 + j] = m[i][j];
}

// ---- one rank-4 GJ step; PO = within-tile offset (compile-time) ----
// Block algebra (reduces to verified scalar GJ at panel=1):
//   C_new = -A_old[:,piv] @ Dinv (zeros on piv rows)   -> colpT, a cols
//   R_old = A_old[piv,:] (zeros on piv cols)           -> rowp
//   interior: a += C_new * R_old  (zeros mask piv row/col)
//   new piv rows = Dinv @ R_old; piv block = Dinv
// Next step's Dinv computed by its owner AFTER its interior update (overlap);
// dreg register copies isolate the in-flight dinv overwrite (mid barrier WAR).
template<int PO>
__device__ __forceinline__ void gj_step(float (&a)[8][8], int kp, int tx, int ty, int R, int Cc,
                                        float* dinv, float (*colpT)[132], float (*rowp)[132]) {
    const int pt = kp >> 1;
    const int k4 = kp * 4;
    const bool isCol = (tx == pt);
    const bool isRow = (ty == pt);
    float dreg[16];
    if (isRow) {
        #pragma unroll
        for (int i = 0; i < 16; ++i) dreg[i] = dinv[i];
    }
    if (isCol) {
        #pragma unroll
        for (int i = 0; i < 8; ++i) {
            int gi = R + i;
            float u0 = 0.f, u1 = 0.f, u2 = 0.f, u3 = 0.f;
            #pragma unroll
            for (int mm = 0; mm < 4; ++mm) {
                float av = a[i][PO + mm];
                u0 += av * dinv[mm * 4 + 0];
                u1 += av * dinv[mm * 4 + 1];
                u2 += av * dinv[mm * 4 + 2];
                u3 += av * dinv[mm * 4 + 3];
            }
            bool inpiv = (gi >= k4) && (gi < k4 + 4);
            float c0 = inpiv ? 0.f : -u0, c1 = inpiv ? 0.f : -u1;
            float c2 = inpiv ? 0.f : -u2, c3 = inpiv ? 0.f : -u3;
            colpT[0][gi] = c0; colpT[1][gi] = c1; colpT[2][gi] = c2; colpT[3][gi] = c3;
            if (!inpiv) { a[i][PO + 0] = c0; a[i][PO + 1] = c1; a[i][PO + 2] = c2; a[i][PO + 3] = c3; }
        }
    }
    if (isRow) {
        #pragma unroll
        for (int m = 0; m < 4; ++m)
            #pragma unroll
            for (int j = 0; j < 8; ++j) {
                int gj = Cc + j;
                bool inpiv = (gj >= k4) && (gj < k4 + 4);
                rowp[m][gj] = inpiv ? 0.0f : a[PO + m][j];
            }
    }
    __syncthreads();
    // interior rank-4 update (zeros in colpT/rowp protect pivot rows/cols)
    #pragma unroll
    for (int m = 0; m < 4; ++m) {
        float4 r0 = *(const float4*)&rowp[m][Cc];
        float4 r1 = *(const float4*)&rowp[m][Cc + 4];
        float rr[8] = {r0.x, r0.y, r0.z, r0.w, r1.x, r1.y, r1.z, r1.w};
        #pragma unroll
        for (int i = 0; i < 8; ++i) {
            float c = colpT[m][R + i];
            #pragma unroll
            for (int j = 0; j < 8; ++j) a[i][j] += c * rr[j];
        }
    }
    // row transform: new piv rows = Dinv @ R_old; pivot block = Dinv
    if (isRow) {
        float nr[4][8];
        #pragma unroll
        for (int m = 0; m < 4; ++m)
            #pragma unroll
            for (int j = 0; j < 8; ++j)
                nr[m][j] = dreg[m * 4 + 0] * rowp[0][Cc + j] + dreg[m * 4 + 1] * rowp[1][Cc + j]
                         + dreg[m * 4 + 2] * rowp[2][Cc + j] + dreg[m * 4 + 3] * rowp[3][Cc + j];
        #pragma unroll
        for (int m = 0; m < 4; ++m)
            #pragma unroll
            for (int j = 0; j < 8; ++j) a[PO + m][j] = nr[m][j];
        if (isCol) {
            #pragma unroll
            for (int m = 0; m < 4; ++m)
                #pragma unroll
                for (int mm = 0; mm < 4; ++mm) a[PO + m][PO + mm] = dreg[m * 4 + mm];
        }
    }
    // next pivot block inverse (owner thread; overlaps other threads' work)
    if (kp < 31) {
        constexpr int NPO = (PO == 0) ? 4 : 0;
        const int nt = (kp + 1) >> 1;
        if (ty == nt && tx == nt) {
            float mmat[4][4];
            #pragma unroll
            for (int i = 0; i < 4; ++i)
                #pragma unroll
                for (int j = 0; j < 4; ++j) mmat[i][j] = a[NPO + i][NPO + j];
            inv4_write(mmat, dinv);
        }
    }
    __syncthreads();
}

// ---- rank-4 blocked register-tile Gauss-Jordan inverse ----
__global__ __launch_bounds__(256) void k_gj(float invtot2) {
    __shared__ float dinv[16];
    __shared__ float colpT[4][132];
    __shared__ float rowp[4][132];
    const int tx = threadIdx.x & 15, ty = threadIdx.x >> 4;
    const int R = ty * 8, Cc = tx * 8;
    float a[8][8];
    #pragma unroll
    for (int i = 0; i < 8; ++i)
        #pragma unroll
        for (int j = 0; j < 8; ++j) {
            int gi = R + i, gj = Cc + j;
            float v = (g_G[gi * DNUM + gj] + g_G[gj * DNUM + gi]) * invtot2;
            if (gi == gj) v += EPSV;
            a[i][j] = v;
        }
    if (tx == 0 && ty == 0) {
        float mmat[4][4];
        #pragma unroll
        for (int i = 0; i < 4; ++i)
            #pragma unroll
            for (int j = 0; j < 4; ++j) mmat[i][j] = a[i][j];
        inv4_write(mmat, dinv);
    }
    __syncthreads();
    for (int kh = 0; kh < 16; ++kh) {
        gj_step<0>(a, kh * 2,     tx, ty, R, Cc, dinv, colpT, rowp);
        gj_step<4>(a, kh * 2 + 1, tx, ty, R, Cc, dinv, colpT, rowp);
    }
    #pragma unroll
    for (int i = 0; i < 8; ++i) {
        *(float4*)(g_P + (size_t)(R + i) * DNUM + Cc)     = make_float4(a[i][0], a[i][1], a[i][2], a[i][3]);
        *(float4*)(g_P + (size_t)(R + i) * DNUM + Cc + 4) = make_float4(a[i][4], a[i][5], a[i][6], a[i][7]);
    }
}

// ---- fused X@P row-dot kernel: blocks 0..7 mean (Pm + r), 8..71 z (q) ----
__global__ __launch_bounds__(256) void k_xpq(const float* __restrict__ z) {
    __shared__ float xs[64][132];
    __shared__ float part[64][33];
    const int t = threadIdx.x;
    const int bi = blockIdx.x;
    const bool mmode = (bi < 8);
    const float* __restrict__ X = mmode ? (const float*)g_mean : z;
    const int row0 = mmode ? bi * 64 : (bi - 8) * 64;
    #pragma unroll
    for (int v = 0; v < 8; ++v) {
        int idx = t + v * 256;
        int r = idx >> 5, f4 = idx & 31;
        float4 val = ((const float4*)X)[(size_t)(row0 + r) * 32 + f4];
        *(float4*)&xs[r][f4 * 4] = val;
    }
    __syncthreads();
    int tx = t & 31, ty = t >> 5;
    float acc[8][4] = {};
    for (int e = 0; e < DNUM; ++e) {
        float4 pv = ((const float4*)g_P)[e * 32 + tx];
        #pragma unroll
        for (int i = 0; i < 8; ++i) {
            float xv = xs[ty * 8 + i][e];
            acc[i][0] += xv * pv.x; acc[i][1] += xv * pv.y;
            acc[i][2] += xv * pv.z; acc[i][3] += xv * pv.w;
        }
    }
    #pragma unroll
    for (int i = 0; i < 8; ++i) {
        int r = ty * 8 + i;
        if (mmode)
            *(float4*)&g_Pm[(size_t)(row0 + r) * DNUM + tx * 4] =
                make_float4(acc[i][0], acc[i][1], acc[i][2], acc[i][3]);
        part[r][tx] = acc[i][0] * xs[r][tx * 4 + 0] + acc[i][1] * xs[r][tx * 4 + 1]
                    + acc[i][2] * xs[r][tx * 4 + 2] + acc[i][3] * xs[r][tx * 4 + 3];
    }
    __syncthreads();
    if (t < 64) {
        float s = 0.f;
        #pragma unroll
        for (int x = 0; x < 32; ++x) s += part[t][x];
        if (mmode) g_r[row0 + t] = s;
        else       g_q[row0 + t] = s;
    }
}

// ---------------- out[b][c] = lp[c] - 0.5*q_b - 0.5*r_c + z_b . Pm_c ----------------
__global__ __launch_bounds__(256) void k_out(const float* __restrict__ z, float* __restrict__ out) {
    __shared__ float zs[64][65];
    __shared__ float ps[64][65];
    int t = threadIdx.x;
    int m0 = blockIdx.y * 64;      // sample rows
    int c0 = blockIdx.x * 64;      // class cols
    int tx = t & 15, ty = t >> 4;
    float acc[4][4] = {};
    for (int kc = 0; kc < 2; ++kc) {
        #pragma unroll
        for (int v = 0; v < 4; ++v) {
            int idx = t + v * 256;
            int r = idx >> 4, f4 = idx & 15;
            float4 zv = ((const float4*)z)[(size_t)(m0 + r) * 32 + kc * 16 + f4];
            zs[r][f4 * 4 + 0] = zv.x; zs[r][f4 * 4 + 1] = zv.y;
            zs[r][f4 * 4 + 2] = zv.z; zs[r][f4 * 4 + 3] = zv.w;
            float4 pv = ((const float4*)g_Pm)[(size_t)(c0 + r) * 32 + kc * 16 + f4];
            ps[r][f4 * 4 + 0] = pv.x; ps[r][f4 * 4 + 1] = pv.y;
            ps[r][f4 * 4 + 2] = pv.z; ps[r][f4 * 4 + 3] = pv.w;
        }
        __syncthreads();
        #pragma unroll 8
        for (int kk = 0; kk < 64; ++kk) {
            float za[4], pb[4];
            #pragma unroll
            for (int i = 0; i < 4; ++i) za[i] = zs[ty * 4 + i][kk];
            #pragma unroll
            for (int j = 0; j < 4; ++j) pb[j] = ps[tx * 4 + j][kk];
            #pragma unroll
            for (int i = 0; i < 4; ++i)
                #pragma unroll
                for (int j = 0; j < 4; ++j)
                    acc[i][j] += za[i] * pb[j];
        }
        __syncthreads();
    }
    int cbase = c0 + tx * 4;
    float4 lp4 = *(const float4*)(g_lp + cbase);
    float4 rv4 = *(const float4*)(g_r + cbase);
    #pragma unroll
    for (int i = 0; i < 4; ++i) {
        int row = m0 + ty * 4 + i;
        float qv = g_q[row];
        float4 o;
        o.x = acc[i][0] + lp4.x - 0.5f * (qv + rv4.x);
        o.y = acc[i][1] + lp4.y - 0.5f * (qv + rv4.y);
        o.z = acc[i][2] + lp4.z - 0.5f * (qv + rv4.z);
        o.w = acc[i][3] + lp4.w - 0.5f * (qv + rv4.w);
        *(float4*)&out[(size_t)row * CNUM + cbase] = o;
    }
}

extern "C" void kernel_launch(void* const* d_in, const int* in_sizes, int n_in,
                              void* d_out, int out_size, void* d_ws, size_t ws_size,
                              hipStream_t stream) {
    const float* z = (const float*)d_in[0];
    const int* y = (const int*)d_in[1];
    float* out = (float*)d_out;
    const int B = in_sizes[0] / DNUM;                 // 4096
    const float total = (float)B + (float)CNUM * EPSV;
    const float logtot = logf(total);

    k_csum<<<17, 256, 0, stream>>>(z, y, logtot);
    k_gpart<<<GPBLK, 256, 0, stream>>>(z);
    k_greduce<<<DNUM * DNUM / 256, 256, 0, stream>>>();
    k_gj<<<1, 256, 0, stream>>>(0.5f / total);
    k_xpq<<<GPBLK, 256, 0, stream>>>(z);
    k_out<<<dim3(CNUM / 64, B / 64), 256, 0, stream>>>(z, out);
}

// Round 11
// 207.021 us; speedup vs baseline: 1.0934x; 1.0934x over previous
//
#include <hip/hip_runtime.h>
#include <cmath>

#define CNUM 512
#define DNUM 128
#define BNUM 4096
#define EPSV 1e-5f
#define GPBLK 72            // (4096 + 512) / 64 split-K partial blocks

// ---- all intermediates in device globals: no d_ws dependence at all ----
__device__ float g_counts[CNUM];
__device__ float g_mean[CNUM * DNUM];
__device__ float g_lp[CNUM];
__device__ float g_G[DNUM * DNUM];
__device__ float g_Gp[GPBLK * DNUM * DNUM];   // split-K partials, 4.7 MB
__device__ float g_P[DNUM * DNUM];
__device__ float g_Pm[CNUM * DNUM];
__device__ float g_r[CNUM];
__device__ float g_q[BNUM];

// ---- class sums + counts + mean + logprior, no global atomics ----
__global__ __launch_bounds__(256) void k_csum(const float* __restrict__ z, const int* __restrict__ y,
                                              float logtot) {
    const int t = threadIdx.x;
    const int bi = blockIdx.x;
    __shared__ float cnt[CNUM];
    cnt[t] = 0.0f; cnt[t + 256] = 0.0f;
    __syncthreads();
    #pragma unroll
    for (int i = 0; i < 16; ++i) atomicAdd(&cnt[y[i * 256 + t]], 1.0f);
    __syncthreads();
    if (bi < 16) {
        __shared__ float acc[CNUM][8];        // 16 KB
        #pragma unroll
        for (int v = 0; v < 16; ++v) {
            int idx = t + v * 256;
            acc[idx >> 3][idx & 7] = 0.0f;
        }
        __syncthreads();
        const int d0 = bi * 8;
        #pragma unroll
        for (int i = 0; i < 16; ++i) {
            int s = i * 256 + t;
            int yy = y[s];
            const float4* zp = (const float4*)(z + (size_t)s * DNUM + d0);
            float4 a = zp[0], b = zp[1];
            float* dst = &acc[yy][0];
            atomicAdd(dst + 0, a.x); atomicAdd(dst + 1, a.y);
            atomicAdd(dst + 2, a.z); atomicAdd(dst + 3, a.w);
            atomicAdd(dst + 4, b.x); atomicAdd(dst + 5, b.y);
            atomicAdd(dst + 6, b.z); atomicAdd(dst + 7, b.w);
        }
        __syncthreads();
        #pragma unroll
        for (int v = 0; v < 2; ++v) {
            int c = t + v * 256;
            float inv = 1.0f / (cnt[c] + EPSV);
            float4 a0 = *(float4*)&acc[c][0];
            float4 a1 = *(float4*)&acc[c][4];
            *(float4*)&g_mean[(size_t)c * DNUM + d0]     = make_float4(a0.x * inv, a0.y * inv, a0.z * inv, a0.w * inv);
            *(float4*)&g_mean[(size_t)c * DNUM + d0 + 4] = make_float4(a1.x * inv, a1.y * inv, a1.z * inv, a1.w * inv);
        }
    } else {
        #pragma unroll
        for (int v = 0; v < 2; ++v) {
            int c = t + v * 256;
            g_counts[c] = cnt[c];
            g_lp[c] = logf(cnt[c] + EPSV) - logtot;
        }
    }
}

// ---- G split-K partial: rows [b*64, b*64+64) of X=[z; mean], weighted ----
__global__ __launch_bounds__(256) void k_gpart(const float* __restrict__ z) {
    __shared__ float xs[64][132];
    __shared__ float ws[64];
    const int t = threadIdx.x;
    const int R0 = blockIdx.x * 64;
    #pragma unroll
    for (int v = 0; v < 8; ++v) {
        int idx = t + v * 256;
        int r = idx >> 5, f4 = idx & 31;
        int row = R0 + r;
        float4 val;
        if (row < BNUM) {
            val = ((const float4*)z)[(size_t)row * 32 + f4];
            if (f4 == 0) ws[r] = 1.0f;
        } else {
            int c = row - BNUM;
            val = ((const float4*)g_mean)[(size_t)c * 32 + f4];
            if (f4 == 0) ws[r] = -(g_counts[c] + 2.0f * EPSV);
        }
        *(float4*)&xs[r][f4 * 4] = val;
    }
    __syncthreads();
    const int tx = t & 15, ty = t >> 4;
    float acc[8][8] = {};
    #pragma unroll
    for (int s = 0; s < 64; ++s) {
        const float4* pa = (const float4*)&xs[s][ty * 8];
        const float4* pb = (const float4*)&xs[s][tx * 8];
        float w = ws[s];
        float4 t0 = pa[0], t1 = pa[1];
        float4 u0 = pb[0], u1 = pb[1];
        float va[8] = {w * t0.x, w * t0.y, w * t0.z, w * t0.w, w * t1.x, w * t1.y, w * t1.z, w * t1.w};
        float vb[8] = {u0.x, u0.y, u0.z, u0.w, u1.x, u1.y, u1.z, u1.w};
        #pragma unroll
        for (int i = 0; i < 8; ++i)
            #pragma unroll
            for (int j = 0; j < 8; ++j)
                acc[i][j] += va[i] * vb[j];
    }
    float* gp = g_Gp + (size_t)blockIdx.x * DNUM * DNUM;
    #pragma unroll
    for (int i = 0; i < 8; ++i) {
        *(float4*)(gp + (size_t)(ty * 8 + i) * DNUM + tx * 8)     = make_float4(acc[i][0], acc[i][1], acc[i][2], acc[i][3]);
        *(float4*)(gp + (size_t)(ty * 8 + i) * DNUM + tx * 8 + 4) = make_float4(acc[i][4], acc[i][5], acc[i][6], acc[i][7]);
    }
}

// ---------------- reduce 72 partials -> g_G ----------------
__global__ __launch_bounds__(256) void k_greduce() {
    int idx = blockIdx.x * 256 + threadIdx.x;   // 16384 threads
    float s = 0.0f;
    #pragma unroll
    for (int p = 0; p < GPBLK; ++p) s += g_Gp[(size_t)p * DNUM * DNUM + idx];
    g_G[idx] = s;
}

// ---- scalar register-tile Gauss-Jordan, ONE barrier per pivot ----
// Same algebra as the verified 2-barrier version (R7, 62us). Publishes are
// UNSCALED old col/row k (pivot slot zeroed) + 1/a[k][k], double-buffered
// (slot k&1). Consumers apply d themselves (cd[i] = -d*colu[i]). Pivot k+1
// is published at the END of step k by its owners from their just-updated
// registers; buffer parity makes the WAR hazard safe with a single barrier.
__global__ __launch_bounds__(256) void k_gj(float invtot2) {
    __shared__ float colu[2][128];
    __shared__ float rowu[2][128];
    __shared__ float dshs[2];
    const int tx = threadIdx.x & 15, ty = threadIdx.x >> 4;
    const int R = ty * 8, Cc = tx * 8;
    float a[8][8];
    #pragma unroll
    for (int i = 0; i < 8; ++i)
        #pragma unroll
        for (int j = 0; j < 8; ++j) {
            int gi = R + i, gj = Cc + j;
            float v = (g_G[gi * DNUM + gj] + g_G[gj * DNUM + gi]) * invtot2;
            if (gi == gj) v += EPSV;
            a[i][j] = v;
        }
    // pre-publish pivot 0 into slot 0
    if (tx == 0) {
        #pragma unroll
        for (int i = 0; i < 8; ++i) { int gi = R + i; colu[0][gi] = (gi == 0) ? 0.f : a[i][0]; }
    }
    if (ty == 0) {
        #pragma unroll
        for (int j = 0; j < 8; ++j) { int gj = Cc + j; rowu[0][gj] = (gj == 0) ? 0.f : a[0][j]; }
    }
    if (tx == 0 && ty == 0) dshs[0] = 1.0f / a[0][0];
    __syncthreads();
    for (int kb = 0; kb < 16; ++kb) {
        #pragma unroll
        for (int ko = 0; ko < 8; ++ko) {
            const int k = kb * 8 + ko;
            const int buf = k & 1;
            const float d = dshs[buf];
            float4 c0 = *(const float4*)&colu[buf][R], c1 = *(const float4*)&colu[buf][R + 4];
            float4 r0 = *(const float4*)&rowu[buf][Cc], r1 = *(const float4*)&rowu[buf][Cc + 4];
            float cd[8] = {-d * c0.x, -d * c0.y, -d * c0.z, -d * c0.w,
                           -d * c1.x, -d * c1.y, -d * c1.z, -d * c1.w};
            float rr[8] = {r0.x, r0.y, r0.z, r0.w, r1.x, r1.y, r1.z, r1.w};
            // interior rank-1 (zeros at pivot slots protect row/col k)
            #pragma unroll
            for (int i = 0; i < 8; ++i)
                #pragma unroll
                for (int j = 0; j < 8; ++j)
                    a[i][j] += cd[i] * rr[j];
            // column k: a[i][k] = -d*old  (rowu[k]=0 kept interior off this col)
            if (tx == kb) {
                #pragma unroll
                for (int i = 0; i < 8; ++i) { int gi = R + i; if (gi != k) a[i][ko] = cd[i]; }
            }
            // row k: a[k][j] *= d  (cd[k]=0 kept interior off this row); diag = d
            if (ty == kb) {
                #pragma unroll
                for (int j = 0; j < 8; ++j) { int gj = Cc + j; if (gj != k) a[ko][j] *= d; }
                if (tx == kb) a[ko][ko] = d;
            }
            // publish pivot k+1 from just-updated registers into the other slot
            if (k < 127) {
                const int nb = buf ^ 1;
                constexpr int nko = (8 + 1) > 8 ? 0 : 0; // placeholder, real below
                if (ko < 7) {
                    const int kn = k + 1;
                    if (tx == kb) {
                        #pragma unroll
                        for (int i = 0; i < 8; ++i) { int gi = R + i; colu[nb][gi] = (gi == kn) ? 0.f : a[i][ko + 1]; }
                    }
                    if (ty == kb) {
                        #pragma unroll
                        for (int j = 0; j < 8; ++j) { int gj = Cc + j; rowu[nb][gj] = (gj == kn) ? 0.f : a[ko + 1][j]; }
                    }
                    if (tx == kb && ty == kb) dshs[nb] = 1.0f / a[ko + 1][ko + 1];
                } else {
                    const int kn = k + 1;        // first pivot of next tile block
                    if (tx == kb + 1) {
                        #pragma unroll
                        for (int i = 0; i < 8; ++i) { int gi = R + i; colu[nb][gi] = (gi == kn) ? 0.f : a[i][0]; }
                    }
                    if (ty == kb + 1) {
                        #pragma unroll
                        for (int j = 0; j < 8; ++j) { int gj = Cc + j; rowu[nb][gj] = (gj == kn) ? 0.f : a[0][j]; }
                    }
                    if (tx == kb + 1 && ty == kb + 1) dshs[nb] = 1.0f / a[0][0];
                }
            }
            __syncthreads();
        }
    }
    #pragma unroll
    for (int i = 0; i < 8; ++i) {
        *(float4*)(g_P + (size_t)(R + i) * DNUM + Cc)     = make_float4(a[i][0], a[i][1], a[i][2], a[i][3]);
        *(float4*)(g_P + (size_t)(R + i) * DNUM + Cc + 4) = make_float4(a[i][4], a[i][5], a[i][6], a[i][7]);
    }
}

// ---- fused X@P row-dot kernel: blocks 0..7 mean (Pm + r), 8..71 z (q) ----
__global__ __launch_bounds__(256) void k_xpq(const float* __restrict__ z) {
    __shared__ float xs[64][132];
    __shared__ float part[64][33];
    const int t = threadIdx.x;
    const int bi = blockIdx.x;
    const bool mmode = (bi < 8);
    const float* __restrict__ X = mmode ? (const float*)g_mean : z;
    const int row0 = mmode ? bi * 64 : (bi - 8) * 64;
    #pragma unroll
    for (int v = 0; v < 8; ++v) {
        int idx = t + v * 256;
        int r = idx >> 5, f4 = idx & 31;
        float4 val = ((const float4*)X)[(size_t)(row0 + r) * 32 + f4];
        *(float4*)&xs[r][f4 * 4] = val;
    }
    __syncthreads();
    int tx = t & 31, ty = t >> 5;
    float acc[8][4] = {};
    for (int e = 0; e < DNUM; ++e) {
        float4 pv = ((const float4*)g_P)[e * 32 + tx];
        #pragma unroll
        for (int i = 0; i < 8; ++i) {
            float xv = xs[ty * 8 + i][e];
            acc[i][0] += xv * pv.x; acc[i][1] += xv * pv.y;
            acc[i][2] += xv * pv.z; acc[i][3] += xv * pv.w;
        }
    }
    #pragma unroll
    for (int i = 0; i < 8; ++i) {
        int r = ty * 8 + i;
        if (mmode)
            *(float4*)&g_Pm[(size_t)(row0 + r) * DNUM + tx * 4] =
                make_float4(acc[i][0], acc[i][1], acc[i][2], acc[i][3]);
        part[r][tx] = acc[i][0] * xs[r][tx * 4 + 0] + acc[i][1] * xs[r][tx * 4 + 1]
                    + acc[i][2] * xs[r][tx * 4 + 2] + acc[i][3] * xs[r][tx * 4 + 3];
    }
    __syncthreads();
    if (t < 64) {
        float s = 0.f;
        #pragma unroll
        for (int x = 0; x < 32; ++x) s += part[t][x];
        if (mmode) g_r[row0 + t] = s;
        else       g_q[row0 + t] = s;
    }
}

// ---------------- out[b][c] = lp[c] - 0.5*q_b - 0.5*r_c + z_b . Pm_c ----------------
__global__ __launch_bounds__(256) void k_out(const float* __restrict__ z, float* __restrict__ out) {
    __shared__ float zs[64][65];
    __shared__ float ps[64][65];
    int t = threadIdx.x;
    int m0 = blockIdx.y * 64;      // sample rows
    int c0 = blockIdx.x * 64;      // class cols
    int tx = t & 15, ty = t >> 4;
    float acc[4][4] = {};
    for (int kc = 0; kc < 2; ++kc) {
        #pragma unroll
        for (int v = 0; v < 4; ++v) {
            int idx = t + v * 256;
            int r = idx >> 4, f4 = idx & 15;
            float4 zv = ((const float4*)z)[(size_t)(m0 + r) * 32 + kc * 16 + f4];
            zs[r][f4 * 4 + 0] = zv.x; zs[r][f4 * 4 + 1] = zv.y;
            zs[r][f4 * 4 + 2] = zv.z; zs[r][f4 * 4 + 3] = zv.w;
            float4 pv = ((const float4*)g_Pm)[(size_t)(c0 + r) * 32 + kc * 16 + f4];
            ps[r][f4 * 4 + 0] = pv.x; ps[r][f4 * 4 + 1] = pv.y;
            ps[r][f4 * 4 + 2] = pv.z; ps[r][f4 * 4 + 3] = pv.w;
        }
        __syncthreads();
        #pragma unroll 8
        for (int kk = 0; kk < 64; ++kk) {
            float za[4], pb[4];
            #pragma unroll
            for (int i = 0; i < 4; ++i) za[i] = zs[ty * 4 + i][kk];
            #pragma unroll
            for (int j = 0; j < 4; ++j) pb[j] = ps[tx * 4 + j][kk];
            #pragma unroll
            for (int i = 0; i < 4; ++i)
                #pragma unroll
                for (int j = 0; j < 4; ++j)
                    acc[i][j] += za[i] * pb[j];
        }
        __syncthreads();
    }
    int cbase = c0 + tx * 4;
    float4 lp4 = *(const float4*)(g_lp + cbase);
    float4 rv4 = *(const float4*)(g_r + cbase);
    #pragma unroll
    for (int i = 0; i < 4; ++i) {
        int row = m0 + ty * 4 + i;
        float qv = g_q[row];
        float4 o;
        o.x = acc[i][0] + lp4.x - 0.5f * (qv + rv4.x);
        o.y = acc[i][1] + lp4.y - 0.5f * (qv + rv4.y);
        o.z = acc[i][2] + lp4.z - 0.5f * (qv + rv4.z);
        o.w = acc[i][3] + lp4.w - 0.5f * (qv + rv4.w);
        *(float4*)&out[(size_t)row * CNUM + cbase] = o;
    }
}

extern "C" void kernel_launch(void* const* d_in, const int* in_sizes, int n_in,
                              void* d_out, int out_size, void* d_ws, size_t ws_size,
                              hipStream_t stream) {
    const float* z = (const float*)d_in[0];
    const int* y = (const int*)d_in[1];
    float* out = (float*)d_out;
    const int B = in_sizes[0] / DNUM;                 // 4096
    const float total = (float)B + (float)CNUM * EPSV;
    const float logtot = logf(total);

    k_csum<<<17, 256, 0, stream>>>(z, y, logtot);
    k_gpart<<<GPBLK, 256, 0, stream>>>(z);
    k_greduce<<<DNUM * DNUM / 256, 256, 0, stream>>>();
    k_gj<<<1, 256, 0, stream>>>(0.5f / total);
    k_xpq<<<GPBLK, 256, 0, stream>>>(z);
    k_out<<<dim3(CNUM / 64, B / 64), 256, 0, stream>>>(z, out);
}